// Round 1
// baseline (30.611 us; speedup 1.0000x reference)
//
#include <hip/hip_runtime.h>
#include <math.h>

// SelfRouting2d — collapsed math:
//   softmax over K of K-identical logits == 1/K exactly -> W2, b2 cancel.
//   out[b,k,u] = (1/S[b]) * sum_i W1[k,u,i] * z[b,i]
//   z[b,i] = sum_n a[b,n]*x[b,i,n],  a[b,n]=||x[b,:,n]||_2,  S[b]=sum_n a[b,n]

#define BB 64
#define IN_UNITS 64
#define NCAPS 2048
#define OUT_PER_B 512   // K=32 * U=16
#define CHUNKS 8
#define TILE_N 256      // n per block in pass 1

__global__ __launch_bounds__(256) void sr_pass1(
    const float* __restrict__ x, float* __restrict__ z_part, float* __restrict__ s_part)
{
  __shared__ __align__(16) float a_lds[TILE_N];
  __shared__ float ztmp[4][IN_UNITS];
  __shared__ float swave[4];

  const int bid   = blockIdx.x;
  const int b     = bid >> 3;
  const int chunk = bid & 7;
  const int n0    = chunk * TILE_N;
  const int tid   = threadIdx.x;

  // ---- phase 1: a[n] = ||x[b,:,n]||, coalesced (lanes span consecutive n)
  const float* xb = x + (size_t)b * IN_UNITS * NCAPS + n0 + tid;
  float ssq = 0.f;
  #pragma unroll
  for (int i = 0; i < IN_UNITS; ++i) {
    float v = xb[(size_t)i * NCAPS];
    ssq = fmaf(v, v, ssq);
  }
  float a = sqrtf(ssq);
  a_lds[tid] = a;

  // wave-reduce a -> S partial (one scalar per block)
  float s = a;
  #pragma unroll
  for (int off = 32; off > 0; off >>= 1) s += __shfl_down(s, off, 64);
  const int lane = tid & 63, w = tid >> 6;
  if (lane == 0) swave[w] = s;
  __syncthreads();
  if (tid == 0)
    s_part[b * CHUNKS + chunk] = swave[0] + swave[1] + swave[2] + swave[3];

  // ---- phase 2: z partial. thread owns (i = tid&63, n-subrange wj = tid>>6),
  // serial 64-n accumulation -> no per-i cross-lane reduce. x tile is L1/L2-warm.
  const int i  = tid & 63;
  const int wj = tid >> 6;
  const float* xrow = x + ((size_t)(b * IN_UNITS + i)) * NCAPS + n0 + wj * 64;
  const float4* xr4 = reinterpret_cast<const float4*>(xrow);
  const float4* a4  = reinterpret_cast<const float4*>(&a_lds[wj * 64]);
  float acc = 0.f;
  #pragma unroll
  for (int j = 0; j < 16; ++j) {
    float4 xv = xr4[j];
    float4 av = a4[j];   // wave-uniform address -> LDS broadcast
    acc = fmaf(xv.x, av.x, acc);
    acc = fmaf(xv.y, av.y, acc);
    acc = fmaf(xv.z, av.z, acc);
    acc = fmaf(xv.w, av.w, acc);
  }
  ztmp[wj][i] = acc;
  __syncthreads();
  if (tid < IN_UNITS) {
    float zz = ztmp[0][tid] + ztmp[1][tid] + ztmp[2][tid] + ztmp[3][tid];
    z_part[(b * CHUNKS + chunk) * IN_UNITS + tid] = zz;
  }
}

__global__ __launch_bounds__(512) void sr_pass2(
    const float* __restrict__ z_part, const float* __restrict__ s_part,
    const float* __restrict__ W1, float* __restrict__ out)
{
  __shared__ __align__(16) float z_lds[IN_UNITS];
  __shared__ float s_inv;
  const int b   = blockIdx.x;
  const int tid = threadIdx.x;

  if (tid < IN_UNITS) {
    float zz = 0.f;
    #pragma unroll
    for (int c = 0; c < CHUNKS; ++c)
      zz += z_part[(b * CHUNKS + c) * IN_UNITS + tid];
    z_lds[tid] = zz;
  } else if (tid == IN_UNITS) {
    float ss = 0.f;
    #pragma unroll
    for (int c = 0; c < CHUNKS; ++c) ss += s_part[b * CHUNKS + c];
    s_inv = 1.0f / ss;
  }
  __syncthreads();

  // thread j = k*16+u : dot(z, W1[j,:]) — W1 row-major (K,U,I) flattens to [j][i]
  const float4* w4 = reinterpret_cast<const float4*>(W1 + (size_t)tid * IN_UNITS);
  const float4* z4 = reinterpret_cast<const float4*>(z_lds);
  float acc = 0.f;
  #pragma unroll
  for (int j = 0; j < 16; ++j) {
    float4 wv = w4[j];
    float4 zv = z4[j];
    acc = fmaf(wv.x, zv.x, acc);
    acc = fmaf(wv.y, zv.y, acc);
    acc = fmaf(wv.z, zv.z, acc);
    acc = fmaf(wv.w, zv.w, acc);
  }
  out[(size_t)b * OUT_PER_B + tid] = acc * s_inv;
}

extern "C" void kernel_launch(void* const* d_in, const int* in_sizes, int n_in,
                              void* d_out, int out_size, void* d_ws, size_t ws_size,
                              hipStream_t stream) {
  const float* x  = (const float*)d_in[0];
  const float* W1 = (const float*)d_in[1];
  // d_in[2] (W2) and d_in[3] (b2) cancel exactly: softmax over the K axis of
  // K-identical logits is uniform 1/K regardless of logit values.
  float* out = (float*)d_out;

  float* z_part = (float*)d_ws;                          // 64*8*64 f32
  float* s_part = z_part + BB * CHUNKS * IN_UNITS;       // 64*8 f32

  sr_pass1<<<dim3(BB * CHUNKS), dim3(256), 0, stream>>>(x, z_part, s_part);
  sr_pass2<<<dim3(BB), dim3(OUT_PER_B), 0, stream>>>(z_part, s_part, W1, out);
}

// Round 2
// 16.019 us; speedup vs baseline: 1.9109x; 1.9109x over previous
//
#include <hip/hip_runtime.h>
#include <math.h>

// SelfRouting2d — collapsed math:
//   softmax over K of K-identical logits == 1/K exactly -> W2, b2 cancel.
//   out[b,k,u] = (1/S[b]) * sum_i W1[k,u,i] * z[b,i]
//   z[b,i] = sum_n a[b,n]*x[b,i,n],  a[b,n]=||x[b,:,n]||_2,  S[b]=sum_n a[b,n]
//
// Pass 1 reads x from HBM exactly once (coalesced 256B/wave), staging the
// 64KB (b,chunk)-tile in LDS [n][i] with 65-float row stride:
//   write xt[tid][i]: bank (tid+i)%32  -> conflict-free
//   read  xt[n][i] (lanes span i):     -> conflict-free; a_lds[n] broadcast

#define BB 64
#define IN_UNITS 64
#define NCAPS 2048
#define OUT_PER_B 512   // K=32 * U=16
#define CHUNKS 8
#define TILE_N 256      // n per block in pass 1

__global__ __launch_bounds__(256) void sr_pass1(
    const float* __restrict__ x, float* __restrict__ z_part, float* __restrict__ s_part)
{
  __shared__ float xt[TILE_N][IN_UNITS + 1];  // 66.6 KB, pad -> conflict-free both ways
  __shared__ float a_lds[TILE_N];
  __shared__ float ztmp[4][IN_UNITS];
  __shared__ float swave[4];

  const int bid   = blockIdx.x;
  const int b     = bid >> 3;
  const int chunk = bid & 7;
  const int n0    = chunk * TILE_N;
  const int tid   = threadIdx.x;

  // ---- phase 1: single global read of the tile; lanes span consecutive n.
  // Compute ssq[n] on the fly and stash x into LDS transposed-ish [n][i].
  const float* xb = x + (size_t)b * IN_UNITS * NCAPS + n0 + tid;
  float ssq = 0.f;
  #pragma unroll
  for (int i = 0; i < IN_UNITS; ++i) {
    float v = xb[(size_t)i * NCAPS];
    xt[tid][i] = v;
    ssq = fmaf(v, v, ssq);
  }
  float a = sqrtf(ssq);
  a_lds[tid] = a;

  // wave-reduce a -> S partial (one scalar per block)
  float s = a;
  #pragma unroll
  for (int off = 32; off > 0; off >>= 1) s += __shfl_down(s, off, 64);
  const int lane = tid & 63, w = tid >> 6;
  if (lane == 0) swave[w] = s;
  __syncthreads();
  if (tid == 0)
    s_part[b * CHUNKS + chunk] = swave[0] + swave[1] + swave[2] + swave[3];

  // ---- phase 2: z partial from LDS. thread owns (i = tid&63, n-subrange wj),
  // serial 64-n accumulation; xt[n][i] conflict-free, a_lds[n] wave-broadcast.
  const int i  = tid & 63;
  const int wj = tid >> 6;
  float acc = 0.f;
  #pragma unroll
  for (int t = 0; t < 64; ++t) {
    const int n = wj * 64 + t;
    acc = fmaf(a_lds[n], xt[n][i], acc);
  }
  ztmp[wj][i] = acc;
  __syncthreads();
  if (tid < IN_UNITS) {
    float zz = ztmp[0][tid] + ztmp[1][tid] + ztmp[2][tid] + ztmp[3][tid];
    z_part[(b * CHUNKS + chunk) * IN_UNITS + tid] = zz;
  }
}

__global__ __launch_bounds__(512) void sr_pass2(
    const float* __restrict__ z_part, const float* __restrict__ s_part,
    const float* __restrict__ W1, float* __restrict__ out)
{
  __shared__ __align__(16) float z_lds[IN_UNITS];
  __shared__ float s_inv;
  const int b   = blockIdx.x;
  const int tid = threadIdx.x;

  if (tid < IN_UNITS) {
    float zz = 0.f;
    #pragma unroll
    for (int c = 0; c < CHUNKS; ++c)
      zz += z_part[(b * CHUNKS + c) * IN_UNITS + tid];
    z_lds[tid] = zz;
  } else if (tid == IN_UNITS) {
    float ss = 0.f;
    #pragma unroll
    for (int c = 0; c < CHUNKS; ++c) ss += s_part[b * CHUNKS + c];
    s_inv = 1.0f / ss;
  }
  __syncthreads();

  // thread j = k*16+u : dot(z, W1[j,:]) — W1 row-major (K,U,I) flattens to [j][i]
  const float4* w4 = reinterpret_cast<const float4*>(W1 + (size_t)tid * IN_UNITS);
  const float4* z4 = reinterpret_cast<const float4*>(z_lds);
  float acc = 0.f;
  #pragma unroll
  for (int j = 0; j < 16; ++j) {
    float4 wv = w4[j];
    float4 zv = z4[j];
    acc = fmaf(wv.x, zv.x, acc);
    acc = fmaf(wv.y, zv.y, acc);
    acc = fmaf(wv.z, zv.z, acc);
    acc = fmaf(wv.w, zv.w, acc);
  }
  out[(size_t)b * OUT_PER_B + tid] = acc * s_inv;
}

extern "C" void kernel_launch(void* const* d_in, const int* in_sizes, int n_in,
                              void* d_out, int out_size, void* d_ws, size_t ws_size,
                              hipStream_t stream) {
  const float* x  = (const float*)d_in[0];
  const float* W1 = (const float*)d_in[1];
  // d_in[2] (W2) and d_in[3] (b2) cancel exactly: softmax over the K axis of
  // K-identical logits is uniform 1/K regardless of logit values.
  float* out = (float*)d_out;

  float* z_part = (float*)d_ws;                          // 64*8*64 f32
  float* s_part = z_part + BB * CHUNKS * IN_UNITS;       // 64*8 f32

  sr_pass1<<<dim3(BB * CHUNKS), dim3(256), 0, stream>>>(x, z_part, s_part);
  sr_pass2<<<dim3(BB), dim3(OUT_PER_B), 0, stream>>>(z_part, s_part, W1, out);
}

// Round 3
// 13.586 us; speedup vs baseline: 2.2531x; 1.1791x over previous
//
#include <hip/hip_runtime.h>
#include <math.h>

// SelfRouting2d — collapsed math:
//   softmax over K of K-identical logits == 1/K exactly -> W2, b2 cancel.
//   out[b,k,u] = (1/S[b]) * sum_i W1[k,u,i] * z[b,i]
//   z[b,i] = sum_n a[b,n]*x[b,i,n],  a[b,n]=||x[b,:,n]||_2,  S[b]=sum_n a[b,n]
//
// Pass 1: reads x from HBM exactly once with float4 loads (1KB/wave-instr).
// LDS tile stored [i][n] (stride 128 floats == 0 mod 32 banks) with XOR quad
// swizzle pos = q ^ (r&7):
//   write (lanes span q, row fixed):   16-lane quarter = 16 perm'd quads -> 2-way (free)
//   read  (lanes span i, quad fixed):  8 addrs x 8-lane broadcast -> all 32 banks, 1 addr each

#define BB 64
#define IN_UNITS 64
#define NCAPS 2048
#define OUT_PER_B 512   // K=32 * U=16
#define CHUNKS 16
#define TILE_N 128      // n per block in pass 1

__global__ __launch_bounds__(256) void sr_pass1(
    const float* __restrict__ x, float* __restrict__ z_part, float* __restrict__ s_part)
{
  __shared__ __align__(16) float xt[IN_UNITS][TILE_N];  // 32KB, swizzled [i][nquad^..]
  __shared__ float4 ssqp[8][32];                        // 4KB  per-(ih,q) ssq partials
  __shared__ __align__(16) float a_lds[TILE_N];
  __shared__ float ztmp[4][IN_UNITS];
  __shared__ float swave[2];

  const int bid   = blockIdx.x;
  const int b     = bid >> 4;          // CHUNKS = 16
  const int chunk = bid & 15;
  const int n0    = chunk * TILE_N;
  const int t     = threadIdx.x;

  const int q  = t & 31;               // quad within row (32 quads = 128 floats)
  const int ih = t >> 5;               // 0..7 -> owns rows ih*8 .. ih*8+7

  // ---- phase 1: single coalesced float4 read of the 32KB tile + ssq on the fly
  const float* xb = x + (size_t)b * IN_UNITS * NCAPS + n0;
  float4 ssq4 = make_float4(0.f, 0.f, 0.f, 0.f);
  #pragma unroll
  for (int j = 0; j < 8; ++j) {
    const int r = ih * 8 + j;
    float4 xv = reinterpret_cast<const float4*>(xb + (size_t)r * NCAPS)[q];
    ssq4.x = fmaf(xv.x, xv.x, ssq4.x);
    ssq4.y = fmaf(xv.y, xv.y, ssq4.y);
    ssq4.z = fmaf(xv.z, xv.z, ssq4.z);
    ssq4.w = fmaf(xv.w, xv.w, ssq4.w);
    reinterpret_cast<float4*>(&xt[r][0])[q ^ (r & 7)] = xv;  // XOR swizzle
  }
  ssqp[ih][q] = ssq4;
  __syncthreads();

  // a[n] = sqrt(sum over the 8 ih-partials); threads 0..127 own one n each
  float a = 0.f;
  if (t < TILE_N) {
    const int nq = t >> 2, c = t & 3;
    float ss = 0.f;
    #pragma unroll
    for (int k = 0; k < 8; ++k)
      ss += reinterpret_cast<const float*>(&ssqp[k][nq])[c];  // bank = t%32, conflict-free
    a = sqrtf(ss);
    a_lds[t] = a;
  }
  // S partial: waves 0,1 hold the 128 a's (others contribute 0)
  float s = a;
  #pragma unroll
  for (int off = 32; off > 0; off >>= 1) s += __shfl_down(s, off, 64);
  if ((t & 63) == 0 && t < 128) swave[t >> 6] = s;
  __syncthreads();
  if (t == 0) s_part[b * CHUNKS + chunk] = swave[0] + swave[1];

  // ---- phase 2: z partial from LDS, float4 reads, conflict-free via swizzle
  const int i  = t & 63;
  const int tg = t >> 6;               // owns quads tg*8 .. tg*8+7
  const float4* a4 = reinterpret_cast<const float4*>(a_lds);
  float acc = 0.f;
  #pragma unroll
  for (int m = 0; m < 8; ++m) {
    const int qq = tg * 8 + m;
    float4 xv = reinterpret_cast<const float4*>(&xt[i][0])[qq ^ (i & 7)];
    float4 av = a4[qq];                // uniform addr -> broadcast
    acc = fmaf(xv.x, av.x, acc);
    acc = fmaf(xv.y, av.y, acc);
    acc = fmaf(xv.z, av.z, acc);
    acc = fmaf(xv.w, av.w, acc);
  }
  ztmp[tg][i] = acc;
  __syncthreads();
  if (t < IN_UNITS) {
    z_part[((size_t)b * CHUNKS + chunk) * IN_UNITS + t] =
        ztmp[0][t] + ztmp[1][t] + ztmp[2][t] + ztmp[3][t];
  }
}

__global__ __launch_bounds__(256) void sr_pass2(
    const float* __restrict__ z_part, const float* __restrict__ s_part,
    const float* __restrict__ W1, float* __restrict__ out)
{
  __shared__ __align__(16) float z_lds[IN_UNITS];
  const int bid = blockIdx.x;
  const int b   = bid >> 3;            // 8 j-groups per b
  const int g   = bid & 7;
  const int t   = threadIdx.x;

  if (t < IN_UNITS) {
    float zz = 0.f;
    #pragma unroll
    for (int c = 0; c < CHUNKS; ++c)
      zz += z_part[((size_t)b * CHUNKS + c) * IN_UNITS + t];
    z_lds[t] = zz;
  }
  float ss = 0.f;
  #pragma unroll
  for (int c = 0; c < CHUNKS; ++c) ss += s_part[b * CHUNKS + c];  // uniform -> scalar loads
  const float sinv = 1.0f / ss;
  __syncthreads();

  // output j = g*64 + (t>>2); 4 threads per output, 16 floats of the dot each.
  // W1 addresses are 16*t floats -> contiguous 64B lane stride, L2-friendly.
  const int jl   = t >> 2;
  const int part = t & 3;
  const int j    = g * 64 + jl;
  const float4* w4 = reinterpret_cast<const float4*>(W1 + (size_t)j * IN_UNITS + part * 16);
  const float4* z4 = reinterpret_cast<const float4*>(z_lds) + part * 4;
  float acc = 0.f;
  #pragma unroll
  for (int jj = 0; jj < 4; ++jj) {
    float4 wv = w4[jj];
    float4 zv = z4[jj];
    acc = fmaf(wv.x, zv.x, acc);
    acc = fmaf(wv.y, zv.y, acc);
    acc = fmaf(wv.z, zv.z, acc);
    acc = fmaf(wv.w, zv.w, acc);
  }
  acc += __shfl_xor(acc, 1);
  acc += __shfl_xor(acc, 2);
  if (part == 0) out[(size_t)b * OUT_PER_B + j] = acc * sinv;
}

extern "C" void kernel_launch(void* const* d_in, const int* in_sizes, int n_in,
                              void* d_out, int out_size, void* d_ws, size_t ws_size,
                              hipStream_t stream) {
  const float* x  = (const float*)d_in[0];
  const float* W1 = (const float*)d_in[1];
  // d_in[2] (W2) and d_in[3] (b2) cancel exactly: softmax over the K axis of
  // K-identical logits is uniform 1/K regardless of logit values.
  float* out = (float*)d_out;

  float* z_part = (float*)d_ws;                          // 64*16*64 f32 (256KB)
  float* s_part = z_part + (size_t)BB * CHUNKS * IN_UNITS;  // 64*16 f32

  sr_pass1<<<dim3(BB * CHUNKS), dim3(256), 0, stream>>>(x, z_part, s_part);
  sr_pass2<<<dim3(BB * 8), dim3(256), 0, stream>>>(z_part, s_part, W1, out);
}